// Round 2
// baseline (721.886 us; speedup 1.0000x reference)
//
#include <hip/hip_runtime.h>
#include <hip/hip_bf16.h>
#include <math.h>

#define N_NODES 10000
#define N_EDGES 160000
// layer1: H=4, C=128 (concat -> 512); layer2: H=2, C=128 (mean -> 128)

// ---------------------------------------------------------------- CSR build
__global__ void count_kernel(const int* __restrict__ dst, int* __restrict__ counts) {
  int e = blockIdx.x * 256 + threadIdx.x;
  if (e < N_EDGES) atomicAdd(&counts[dst[e]], 1);
}

__global__ void scan_kernel(const int* __restrict__ counts, int* __restrict__ offsets,
                            int* __restrict__ cursor) {
  __shared__ int sh[256];
  __shared__ int carry_s;
  int t = threadIdx.x;
  if (t == 0) carry_s = 0;
  __syncthreads();
  for (int base = 0; base < N_NODES; base += 256) {
    int i = base + t;
    int val = (i < N_NODES) ? counts[i] : 0;
    sh[t] = val;
    __syncthreads();
    for (int offd = 1; offd < 256; offd <<= 1) {
      int tmp = (t >= offd) ? sh[t - offd] : 0;
      __syncthreads();
      sh[t] += tmp;
      __syncthreads();
    }
    int excl = carry_s + sh[t] - val;
    if (i < N_NODES) { offsets[i] = excl; cursor[i] = excl; }
    __syncthreads();
    if (t == 255) carry_s += sh[255];
    __syncthreads();
  }
  if (t == 0) offsets[N_NODES] = carry_s;
}

__global__ void fill_kernel(const int* __restrict__ src, const int* __restrict__ dst,
                            int* __restrict__ cursor, int* __restrict__ csr_src,
                            int* __restrict__ csr_eid) {
  int e = blockIdx.x * 256 + threadIdx.x;
  if (e < N_EDGES) {
    int slot = atomicAdd(&cursor[dst[e]], 1);
    csr_src[slot] = src[e];
    csr_eid[slot] = e;
  }
}

// ---------------------------------------------------------------- fp32 GEMM
// C[M,N] = A[M,K] @ B[K,N] + bias[N]; N % 64 == 0, K % 16 == 0.
#define BM 64
#define BN 64
#define BK 16

__global__ __launch_bounds__(256) void gemm_bias(
    const float* __restrict__ A, const float* __restrict__ B,
    const float* __restrict__ bias, float* __restrict__ C,
    int M, int N, int K) {
  __shared__ float As[BM][BK + 1];
  __shared__ __align__(16) float Bs[BK][BN];
  const int tid = threadIdx.x;
  const int tx = tid & 15, ty = tid >> 4;
  const int row0 = blockIdx.y * BM;
  const int col0 = blockIdx.x * BN;
  float acc[4][4] = {};
  for (int k0 = 0; k0 < K; k0 += BK) {
    {
      int ar = tid >> 2;             // 0..63
      int ac = (tid & 3) << 2;       // 0,4,8,12
      int gr = row0 + ar;
      float4 av = make_float4(0.f, 0.f, 0.f, 0.f);
      if (gr < M) av = *(const float4*)(A + (size_t)gr * K + k0 + ac);
      As[ar][ac] = av.x; As[ar][ac + 1] = av.y; As[ar][ac + 2] = av.z; As[ar][ac + 3] = av.w;
      int br = tid >> 4;             // 0..15
      int bc = (tid & 15) << 2;      // 0..60
      float4 bv = *(const float4*)(B + (size_t)(k0 + br) * N + col0 + bc);
      Bs[br][bc] = bv.x; Bs[br][bc + 1] = bv.y; Bs[br][bc + 2] = bv.z; Bs[br][bc + 3] = bv.w;
    }
    __syncthreads();
#pragma unroll
    for (int kk = 0; kk < BK; ++kk) {
      float a0 = As[ty * 4 + 0][kk];
      float a1 = As[ty * 4 + 1][kk];
      float a2 = As[ty * 4 + 2][kk];
      float a3 = As[ty * 4 + 3][kk];
      float4 b = *(const float4*)&Bs[kk][tx * 4];
      acc[0][0] += a0 * b.x; acc[0][1] += a0 * b.y; acc[0][2] += a0 * b.z; acc[0][3] += a0 * b.w;
      acc[1][0] += a1 * b.x; acc[1][1] += a1 * b.y; acc[1][2] += a1 * b.z; acc[1][3] += a1 * b.w;
      acc[2][0] += a2 * b.x; acc[2][1] += a2 * b.y; acc[2][2] += a2 * b.z; acc[2][3] += a2 * b.w;
      acc[3][0] += a3 * b.x; acc[3][1] += a3 * b.y; acc[3][2] += a3 * b.z; acc[3][3] += a3 * b.w;
    }
    __syncthreads();
  }
  float4 bb = *(const float4*)(bias + col0 + tx * 4);
#pragma unroll
  for (int i = 0; i < 4; ++i) {
    int gr = row0 + ty * 4 + i;
    if (gr < M) {
      float4 o;
      o.x = acc[i][0] + bb.x; o.y = acc[i][1] + bb.y;
      o.z = acc[i][2] + bb.z; o.w = acc[i][3] + bb.w;
      *(float4*)(C + (size_t)gr * N + col0 + tx * 4) = o;
    }
  }
}

// ---------------------------------------------------------------- edge logits
// one wave per edge; alpha[e,h] = dot(q[dst,h,:], k[src,h,:]) * scale, C = 128
__global__ __launch_bounds__(256) void edge_alpha(
    const float* __restrict__ q, const float* __restrict__ k,
    const int* __restrict__ src, const int* __restrict__ dst,
    float* __restrict__ alpha, int H, float scale) {
  int wid = blockIdx.x * 4 + (threadIdx.x >> 6);
  int lane = threadIdx.x & 63;
  if (wid >= N_EDGES) return;
  int s = src[wid], d = dst[wid];
  const float* qd = q + (size_t)d * H * 128;
  const float* ks = k + (size_t)s * H * 128;
  for (int h = 0; h < H; ++h) {
    float p = qd[h * 128 + lane] * ks[h * 128 + lane]
            + qd[h * 128 + 64 + lane] * ks[h * 128 + 64 + lane];
#pragma unroll
    for (int o = 32; o; o >>= 1) p += __shfl_xor(p, o);
    if (lane == 0) alpha[(size_t)wid * H + h] = p * scale;
  }
}

// ---------------------------------------------------------------- aggregation
// one wave per (node, head). MODE 0: out holds skip s1, do out = relu(out+attn)
// (concat layout). MODE 1: atomicAdd(out[n,c], attn*outscale) (head mean).
template <int MODE>
__global__ __launch_bounds__(256) void aggregate(
    const float* __restrict__ v, const float* __restrict__ alpha,
    const int* __restrict__ offsets, const int* __restrict__ csr_src,
    const int* __restrict__ csr_eid, float* __restrict__ out,
    int H, float outscale) {
  int w = blockIdx.x * 4 + (threadIdx.x >> 6);
  int lane = threadIdx.x & 63;
  if (w >= N_NODES * H) return;
  int n = w / H, h = w - n * H;
  int beg = offsets[n], end = offsets[n + 1];
  float m = -INFINITY;
  for (int j = beg + lane; j < end; j += 64)
    m = fmaxf(m, alpha[(size_t)csr_eid[j] * H + h]);
#pragma unroll
  for (int o = 32; o; o >>= 1) m = fmaxf(m, __shfl_xor(m, o));
  float acc0 = 0.f, acc1 = 0.f, denom = 0.f;
  for (int j = beg; j < end; ++j) {
    float a = alpha[(size_t)csr_eid[j] * H + h];
    float p = expf(a - m);
    const float* vs = v + ((size_t)csr_src[j] * H + h) * 128;
    acc0 += p * vs[lane];
    acc1 += p * vs[64 + lane];
    denom += p;
  }
  denom += 1e-16f;
  float r0 = acc0 / denom, r1 = acc1 / denom;
  if (MODE == 0) {
    float* o = out + ((size_t)n * H + h) * 128;
    o[lane] = fmaxf(o[lane] + r0, 0.f);
    o[64 + lane] = fmaxf(o[64 + lane] + r1, 0.f);
  } else {
    float* o = out + (size_t)n * 128;
    atomicAdd(&o[lane], r0 * outscale);
    atomicAdd(&o[64 + lane], r1 * outscale);
  }
}

// ---------------------------------------------------------------- launch
extern "C" void kernel_launch(void* const* d_in, const int* in_sizes, int n_in,
                              void* d_out, int out_size, void* d_ws, size_t ws_size,
                              hipStream_t stream) {
  const float* x   = (const float*)d_in[0];
  const int*   ei  = (const int*)d_in[1];
  const float* Wq1 = (const float*)d_in[2];  const float* bq1 = (const float*)d_in[3];
  const float* Wk1 = (const float*)d_in[4];  const float* bk1 = (const float*)d_in[5];
  const float* Wv1 = (const float*)d_in[6];  const float* bv1 = (const float*)d_in[7];
  const float* Ws1 = (const float*)d_in[8];  const float* bs1 = (const float*)d_in[9];
  const float* Wq2 = (const float*)d_in[10]; const float* bq2 = (const float*)d_in[11];
  const float* Wk2 = (const float*)d_in[12]; const float* bk2 = (const float*)d_in[13];
  const float* Wv2 = (const float*)d_in[14]; const float* bv2 = (const float*)d_in[15];
  const float* Ws2 = (const float*)d_in[16]; const float* bs2 = (const float*)d_in[17];
  float* out = (float*)d_out;

  const int* src = ei;
  const int* dst = ei + N_EDGES;

  char* ws = (char*)d_ws;
  size_t off = 0;
  auto take = [&](size_t bytes) -> void* {
    void* p = ws + off;
    off = (off + bytes + 255) & ~(size_t)255;
    return p;
  };
  int* counts    = (int*)take(N_NODES * 4);
  int* offsets   = (int*)take((N_NODES + 1) * 4);
  int* cursor    = (int*)take(N_NODES * 4);
  int* csr_src   = (int*)take(N_EDGES * 4);
  int* csr_eid   = (int*)take(N_EDGES * 4);
  float* q1      = (float*)take((size_t)N_NODES * 512 * 4);
  float* k1      = (float*)take((size_t)N_NODES * 512 * 4);
  float* v1      = (float*)take((size_t)N_NODES * 512 * 4);
  float* hb      = (float*)take((size_t)N_NODES * 512 * 4);  // s1, then h (in place)
  float* alpha1  = (float*)take((size_t)N_EDGES * 4 * 4);
  float* q2      = (float*)take((size_t)N_NODES * 256 * 4);
  float* k2      = (float*)take((size_t)N_NODES * 256 * 4);
  float* v2      = (float*)take((size_t)N_NODES * 256 * 4);
  float* alpha2  = (float*)take((size_t)N_EDGES * 2 * 4);
  (void)ws_size; // total ~118 MB

  const float scale = 0.08838834764831845f;  // 1/sqrt(128)

  // CSR by dst (edge_index is constant but we rebuild every call per harness rules)
  hipMemsetAsync(counts, 0, N_NODES * 4, stream);
  count_kernel<<<(N_EDGES + 255) / 256, 256, 0, stream>>>(dst, counts);
  scan_kernel<<<1, 256, 0, stream>>>(counts, offsets, cursor);
  fill_kernel<<<(N_EDGES + 255) / 256, 256, 0, stream>>>(src, dst, cursor, csr_src, csr_eid);

  // ---- layer 1 projections
  dim3 g1(512 / BN, (N_NODES + BM - 1) / BM);
  gemm_bias<<<g1, 256, 0, stream>>>(x, Wq1, bq1, q1, N_NODES, 512, 128);
  gemm_bias<<<g1, 256, 0, stream>>>(x, Wk1, bk1, k1, N_NODES, 512, 128);
  gemm_bias<<<g1, 256, 0, stream>>>(x, Wv1, bv1, v1, N_NODES, 512, 128);
  gemm_bias<<<g1, 256, 0, stream>>>(x, Ws1, bs1, hb, N_NODES, 512, 128);

  // ---- layer 1 attention
  edge_alpha<<<(N_EDGES + 3) / 4, 256, 0, stream>>>(q1, k1, src, dst, alpha1, 4, scale);
  aggregate<0><<<(N_NODES * 4 + 3) / 4, 256, 0, stream>>>(v1, alpha1, offsets, csr_src,
                                                          csr_eid, hb, 4, 1.0f);

  // ---- layer 2 projections (input hb = relu'd layer-1 output, K=512)
  dim3 g2(256 / BN, (N_NODES + BM - 1) / BM);
  gemm_bias<<<g2, 256, 0, stream>>>(hb, Wq2, bq2, q2, N_NODES, 256, 512);
  gemm_bias<<<g2, 256, 0, stream>>>(hb, Wk2, bk2, k2, N_NODES, 256, 512);
  gemm_bias<<<g2, 256, 0, stream>>>(hb, Wv2, bv2, v2, N_NODES, 256, 512);
  dim3 g3(128 / BN, (N_NODES + BM - 1) / BM);
  gemm_bias<<<g3, 256, 0, stream>>>(hb, Ws2, bs2, out, N_NODES, 128, 512);  // skip -> out

  // ---- layer 2 attention (mean over 2 heads, accumulate onto skip)
  edge_alpha<<<(N_EDGES + 3) / 4, 256, 0, stream>>>(q2, k2, src, dst, alpha2, 2, scale);
  aggregate<1><<<(N_NODES * 2 + 3) / 4, 256, 0, stream>>>(v2, alpha2, offsets, csr_src,
                                                          csr_eid, out, 2, 0.5f);
}

// Round 12
// 396.643 us; speedup vs baseline: 1.8200x; 1.8200x over previous
//
#include <hip/hip_runtime.h>
#include <hip/hip_bf16.h>
#include <math.h>

#define N_NODES 10000
#define N_EDGES 160000
// layer1: H=4, C=128 (concat -> 512); layer2: H=2, C=128 (mean -> 128)

typedef short v8s __attribute__((ext_vector_type(8)));
typedef float v4f __attribute__((ext_vector_type(4)));

// ---------------------------------------------------------------- CSR build
__global__ void zero_kernel(int* __restrict__ counts) {
  int i = blockIdx.x * 256 + threadIdx.x;
  if (i < N_NODES) counts[i] = 0;
}

__global__ void count_kernel(const int* __restrict__ dst, int* __restrict__ counts) {
  int e = blockIdx.x * 256 + threadIdx.x;
  if (e < N_EDGES) atomicAdd(&counts[dst[e]], 1);
}

__global__ void scan_kernel(const int* __restrict__ counts, int* __restrict__ offsets,
                            int* __restrict__ cursor) {
  __shared__ int sh[256];
  __shared__ int carry_s;
  int t = threadIdx.x;
  if (t == 0) carry_s = 0;
  __syncthreads();
  for (int base = 0; base < N_NODES; base += 256) {
    int i = base + t;
    int val = (i < N_NODES) ? counts[i] : 0;
    sh[t] = val;
    __syncthreads();
    for (int offd = 1; offd < 256; offd <<= 1) {
      int tmp = (t >= offd) ? sh[t - offd] : 0;
      __syncthreads();
      sh[t] += tmp;
      __syncthreads();
    }
    int excl = carry_s + sh[t] - val;
    if (i < N_NODES) { offsets[i] = excl; cursor[i] = excl; }
    __syncthreads();
    if (t == 255) carry_s += sh[255];
    __syncthreads();
  }
  if (t == 0) offsets[N_NODES] = carry_s;
}

__global__ void fill_kernel(const int* __restrict__ src, const int* __restrict__ dst,
                            int* __restrict__ cursor, int* __restrict__ csr_src) {
  int e = blockIdx.x * 256 + threadIdx.x;
  if (e < N_EDGES) {
    int slot = atomicAdd(&cursor[dst[e]], 1);
    csr_src[slot] = src[e];
  }
}

// ---------------------------------------------------------------- prep (bf16 convert + weight transpose-pack)
#define PREP_TOTAL (1280000 + 196608 + 65536 + 393216 + 65536 + 1536 + 768)
__global__ __launch_bounds__(256) void prep_kernel(
    const float* __restrict__ x,
    const float* __restrict__ Wq1, const float* __restrict__ Wk1,
    const float* __restrict__ Wv1, const float* __restrict__ Ws1,
    const float* __restrict__ Wq2, const float* __restrict__ Wk2,
    const float* __restrict__ Wv2, const float* __restrict__ Ws2,
    const float* __restrict__ bq1, const float* __restrict__ bk1,
    const float* __restrict__ bv1,
    const float* __restrict__ bq2, const float* __restrict__ bk2,
    const float* __restrict__ bv2,
    __hip_bfloat16* __restrict__ xb,
    __hip_bfloat16* __restrict__ Wt1, __hip_bfloat16* __restrict__ Wst1,
    __hip_bfloat16* __restrict__ Wt2, __hip_bfloat16* __restrict__ Wst2,
    float* __restrict__ b1, float* __restrict__ b2)
{
  int t = blockIdx.x * 256 + threadIdx.x;
  if (t >= PREP_TOTAL) return;
  if (t < 1280000) { xb[t] = __float2bfloat16(x[t]); return; }
  t -= 1280000;
  if (t < 196608) {                       // Wt1[n][k] = W[k][n], N=512 each, K=128
    int s = t / 65536, r = t % 65536;
    int n = r >> 7, k = r & 127;
    const float* W = (s == 0) ? Wq1 : (s == 1) ? Wk1 : Wv1;
    Wt1[(size_t)(s * 512 + n) * 128 + k] = __float2bfloat16(W[k * 512 + n]);
    return;
  }
  t -= 196608;
  if (t < 65536) {                        // Wst1 [512][128]
    int n = t >> 7, k = t & 127;
    Wst1[t] = __float2bfloat16(Ws1[k * 512 + n]);
    return;
  }
  t -= 65536;
  if (t < 393216) {                       // Wt2 [768][512], N=256 each, K=512
    int s = t / 131072, r = t % 131072;
    int n = r >> 9, k = r & 511;
    const float* W = (s == 0) ? Wq2 : (s == 1) ? Wk2 : Wv2;
    Wt2[(size_t)(s * 256 + n) * 512 + k] = __float2bfloat16(W[k * 256 + n]);
    return;
  }
  t -= 393216;
  if (t < 65536) {                        // Wst2 [128][512]
    int n = t >> 9, k = t & 511;
    Wst2[t] = __float2bfloat16(Ws2[k * 128 + n]);
    return;
  }
  t -= 65536;
  if (t < 1536) { b1[t] = (t < 512) ? bq1[t] : (t < 1024) ? bk1[t - 512] : bv1[t - 1024]; return; }
  t -= 1536;
  b2[t] = (t < 256) ? bq2[t] : (t < 512) ? bk2[t - 256] : bv2[t - 512];
}

// ---------------------------------------------------------------- bf16 MFMA GEMM
// C[M,N] = A[M,K](bf16,row-major) @ Bt[N,K](bf16 = B^T row-major) + bias.
// 128x128 tile, 4 waves (2x2), each wave 64x64 = 4x4 frags of 16x16x32.
#define GBM 128
#define GBN 128
#define GBK 32
#define LSTR 56

__device__ __forceinline__ void store_c(float* p, float v) { *p = v; }
__device__ __forceinline__ void store_c(__hip_bfloat16* p, float v) { *p = __float2bfloat16(v); }

template <typename OutT>
__global__ __launch_bounds__(256) void gemm_mfma(
    const __hip_bfloat16* __restrict__ A, const __hip_bfloat16* __restrict__ Bt,
    const float* __restrict__ bias, OutT* __restrict__ C,
    int M, int N, int K)
{
  __shared__ __hip_bfloat16 As[GBM][LSTR];
  __shared__ __hip_bfloat16 Bs[GBN][LSTR];
  const int tid = threadIdx.x;
  const int lane = tid & 63;
  const int w = tid >> 6;
  const int wm = (w >> 1) * 64, wn = (w & 1) * 64;
  const int row0 = blockIdx.y * GBM;
  const int col0 = blockIdx.x * GBN;

  v4f acc[4][4] = {};

  const int srow = tid >> 1;            // 0..127
  const int shalf = (tid & 1) * 16;     // bf16 elem offset: 0 or 16

  const int rA = lane & 15;
  const int kk = (lane >> 4) * 8;

  for (int k0 = 0; k0 < K; k0 += GBK) {
    {
      int gr = row0 + srow;
      v8s av0 = {}, av1 = {};
      if (gr < M) {
        const __hip_bfloat16* ap = A + (size_t)gr * K + k0 + shalf;
        av0 = *(const v8s*)ap;
        av1 = *(const v8s*)(ap + 8);
      }
      *(v8s*)&As[srow][shalf]     = av0;
      *(v8s*)&As[srow][shalf + 8] = av1;
      const __hip_bfloat16* bp = Bt + (size_t)(col0 + srow) * K + k0 + shalf;
      v8s bv0 = *(const v8s*)bp;
      v8s bv1 = *(const v8s*)(bp + 8);
      *(v8s*)&Bs[srow][shalf]     = bv0;
      *(v8s*)&Bs[srow][shalf + 8] = bv1;
    }
    __syncthreads();
    v8s af[4], bf[4];
#pragma unroll
    for (int i = 0; i < 4; ++i) {
      af[i] = *(const v8s*)&As[wm + i * 16 + rA][kk];
      bf[i] = *(const v8s*)&Bs[wn + i * 16 + rA][kk];
    }
#pragma unroll
    for (int i = 0; i < 4; ++i)
#pragma unroll
      for (int j = 0; j < 4; ++j)
        acc[i][j] = __builtin_amdgcn_mfma_f32_16x16x32_bf16(af[i], bf[j], acc[i][j], 0, 0, 0);
    __syncthreads();
  }

  // epilogue: C/D layout col = lane&15, row = (lane>>4)*4 + r   [m89 verified]
  const int cr = (lane >> 4) * 4;
  const int cc = lane & 15;
#pragma unroll
  for (int j = 0; j < 4; ++j) {
    int gcol = col0 + wn + j * 16 + cc;
    float bb = bias[gcol];
#pragma unroll
    for (int i = 0; i < 4; ++i) {
      int gr0 = row0 + wm + i * 16 + cr;
#pragma unroll
      for (int r = 0; r < 4; ++r) {
        int grow = gr0 + r;
        if (grow < M) store_c(&C[(size_t)grow * N + gcol], acc[i][j][r] + bb);
      }
    }
  }
}

// ---------------------------------------------------------------- fused attention (online softmax)
// layer1: one wave per (node, head). qkv1 [N][1536] bf16 (q|k|v each 512).
// hb[n][512] = relu(s1 + attn) as bf16.
__global__ __launch_bounds__(256) void attn_l1(
    const __hip_bfloat16* __restrict__ qkv, const float* __restrict__ s1,
    const int* __restrict__ offsets, const int* __restrict__ csr_src,
    __hip_bfloat16* __restrict__ hb)
{
  int wid = blockIdx.x * 4 + (threadIdx.x >> 6);
  int lane = threadIdx.x & 63;
  if (wid >= N_NODES * 4) return;
  int n = wid >> 2, h = wid & 3;
  const float scale = 0.08838834764831845f;  // 1/sqrt(128)

  __hip_bfloat162 qq = *(const __hip_bfloat162*)(qkv + (size_t)n * 1536 + h * 128 + lane * 2);
  float q0 = __bfloat162float(qq.x), q1 = __bfloat162float(qq.y);

  int beg = offsets[n], end = offsets[n + 1];
  float m = -INFINITY, denom = 0.f, a0 = 0.f, a1 = 0.f;
  for (int j = beg; j < end; ++j) {
    int s = csr_src[j];
    const __hip_bfloat16* kp = qkv + (size_t)s * 1536 + 512 + h * 128 + lane * 2;
    __hip_bfloat162 kv = *(const __hip_bfloat162*)kp;
    __hip_bfloat162 vv = *(const __hip_bfloat162*)(kp + 512);
    float p = q0 * __bfloat162float(kv.x) + q1 * __bfloat162float(kv.y);
#pragma unroll
    for (int o = 32; o; o >>= 1) p += __shfl_xor(p, o);
    p *= scale;
    float mn = fmaxf(m, p);
    float sc = __expf(m - mn);      // first iter: exp(-inf)=0
    float pe = __expf(p - mn);
    denom = denom * sc + pe;
    a0 = a0 * sc + pe * __bfloat162float(vv.x);
    a1 = a1 * sc + pe * __bfloat162float(vv.y);
    m = mn;
  }
  float inv = 1.f / (denom + 1e-16f);
  const float* sp = s1 + (size_t)n * 512 + h * 128 + lane * 2;
  float r0 = fmaxf(sp[0] + a0 * inv, 0.f);
  float r1 = fmaxf(sp[1] + a1 * inv, 0.f);
  __hip_bfloat162 o2;
  o2.x = __float2bfloat16(r0); o2.y = __float2bfloat16(r1);
  *(__hip_bfloat162*)(hb + (size_t)n * 512 + h * 128 + lane * 2) = o2;
}

// layer2: one wave per node, loops h=0,1; PURE WRITE: out = s2 + 0.5*sum_h attn.
// (round-11 failure: out was read-modify-written across dispatches; d_out is now
//  write-only so the kernel is independent of d_out's initial state.)
__global__ __launch_bounds__(256) void attn_l2(
    const __hip_bfloat16* __restrict__ qkv,   // [N][768] (q|k|v each 256)
    const float* __restrict__ s2,             // [N][128] skip (ws)
    const int* __restrict__ offsets, const int* __restrict__ csr_src,
    float* __restrict__ out)
{
  int n = blockIdx.x * 4 + (threadIdx.x >> 6);
  int lane = threadIdx.x & 63;
  if (n >= N_NODES) return;
  const float scale = 0.08838834764831845f;
  int beg = offsets[n], end = offsets[n + 1];
  float sum0 = 0.f, sum1 = 0.f;
#pragma unroll
  for (int h = 0; h < 2; ++h) {
    __hip_bfloat162 qq = *(const __hip_bfloat162*)(qkv + (size_t)n * 768 + h * 128 + lane * 2);
    float q0 = __bfloat162float(qq.x), q1 = __bfloat162float(qq.y);
    float m = -INFINITY, denom = 0.f, a0 = 0.f, a1 = 0.f;
    for (int j = beg; j < end; ++j) {
      int s = csr_src[j];
      const __hip_bfloat16* kp = qkv + (size_t)s * 768 + 256 + h * 128 + lane * 2;
      __hip_bfloat162 kv = *(const __hip_bfloat162*)kp;
      __hip_bfloat162 vv = *(const __hip_bfloat162*)(kp + 256);
      float p = q0 * __bfloat162float(kv.x) + q1 * __bfloat162float(kv.y);
#pragma unroll
      for (int o = 32; o; o >>= 1) p += __shfl_xor(p, o);
      p *= scale;
      float mn = fmaxf(m, p);
      float sc = __expf(m - mn);
      float pe = __expf(p - mn);
      denom = denom * sc + pe;
      a0 = a0 * sc + pe * __bfloat162float(vv.x);
      a1 = a1 * sc + pe * __bfloat162float(vv.y);
      m = mn;
    }
    float inv = 1.f / (denom + 1e-16f);
    sum0 += a0 * inv;
    sum1 += a1 * inv;
  }
  const float* sp2 = s2 + (size_t)n * 128 + lane * 2;
  float* op = out + (size_t)n * 128 + lane * 2;
  op[0] = sp2[0] + 0.5f * sum0;
  op[1] = sp2[1] + 0.5f * sum1;
}

// ---------------------------------------------------------------- launch
extern "C" void kernel_launch(void* const* d_in, const int* in_sizes, int n_in,
                              void* d_out, int out_size, void* d_ws, size_t ws_size,
                              hipStream_t stream) {
  const float* x   = (const float*)d_in[0];
  const int*   ei  = (const int*)d_in[1];
  const float* Wq1 = (const float*)d_in[2];  const float* bq1 = (const float*)d_in[3];
  const float* Wk1 = (const float*)d_in[4];  const float* bk1 = (const float*)d_in[5];
  const float* Wv1 = (const float*)d_in[6];  const float* bv1 = (const float*)d_in[7];
  const float* Ws1 = (const float*)d_in[8];  const float* bs1 = (const float*)d_in[9];
  const float* Wq2 = (const float*)d_in[10]; const float* bq2 = (const float*)d_in[11];
  const float* Wk2 = (const float*)d_in[12]; const float* bk2 = (const float*)d_in[13];
  const float* Wv2 = (const float*)d_in[14]; const float* bv2 = (const float*)d_in[15];
  const float* Ws2 = (const float*)d_in[16]; const float* bs2 = (const float*)d_in[17];
  float* out = (float*)d_out;

  const int* src = ei;
  const int* dst = ei + N_EDGES;

  char* ws = (char*)d_ws;
  size_t off = 0;
  auto take = [&](size_t bytes) -> void* {
    void* p = ws + off;
    off = (off + bytes + 255) & ~(size_t)255;
    return p;
  };
  int* counts  = (int*)take(N_NODES * 4);
  int* offsets = (int*)take((N_NODES + 1) * 4);
  int* cursor  = (int*)take(N_NODES * 4);
  int* csr_src = (int*)take(N_EDGES * 4);
  __hip_bfloat16* xb   = (__hip_bfloat16*)take((size_t)N_NODES * 128 * 2);
  __hip_bfloat16* Wt1  = (__hip_bfloat16*)take((size_t)1536 * 128 * 2);
  __hip_bfloat16* Wst1 = (__hip_bfloat16*)take((size_t)512 * 128 * 2);
  __hip_bfloat16* Wt2  = (__hip_bfloat16*)take((size_t)768 * 512 * 2);
  __hip_bfloat16* Wst2 = (__hip_bfloat16*)take((size_t)128 * 512 * 2);
  float* b1 = (float*)take(1536 * 4);
  float* b2 = (float*)take(768 * 4);
  __hip_bfloat16* qkv1 = (__hip_bfloat16*)take((size_t)N_NODES * 1536 * 2);
  float*          s1   = (float*)take((size_t)N_NODES * 512 * 4);
  __hip_bfloat16* hb   = (__hip_bfloat16*)take((size_t)N_NODES * 512 * 2);
  __hip_bfloat16* qkv2 = (__hip_bfloat16*)take((size_t)N_NODES * 768 * 2);
  float*          s2   = (float*)take((size_t)N_NODES * 128 * 4);
  (void)ws_size;  // ~87 MB (round-2 kernel used ~118 MB successfully)

  // CSR by dst (all kernel dispatches; no memset nodes in the graph)
  zero_kernel<<<(N_NODES + 255) / 256, 256, 0, stream>>>(counts);
  count_kernel<<<(N_EDGES + 255) / 256, 256, 0, stream>>>(dst, counts);
  scan_kernel<<<1, 256, 0, stream>>>(counts, offsets, cursor);
  fill_kernel<<<(N_EDGES + 255) / 256, 256, 0, stream>>>(src, dst, cursor, csr_src);

  // bf16 conversion + weight transpose-pack (one kernel)
  prep_kernel<<<(PREP_TOTAL + 255) / 256, 256, 0, stream>>>(
      x, Wq1, Wk1, Wv1, Ws1, Wq2, Wk2, Wv2, Ws2,
      bq1, bk1, bv1, bq2, bk2, bv2,
      xb, Wt1, Wst1, Wt2, Wst2, b1, b2);

  const int MBLK = (N_NODES + GBM - 1) / GBM;  // 79

  // layer 1 projections: qkv (bf16 out) + skip s1 (fp32 out)
  gemm_mfma<__hip_bfloat16><<<dim3(1536 / GBN, MBLK), 256, 0, stream>>>(
      xb, Wt1, b1, qkv1, N_NODES, 1536, 128);
  gemm_mfma<float><<<dim3(512 / GBN, MBLK), 256, 0, stream>>>(
      xb, Wst1, bs1, s1, N_NODES, 512, 128);

  // layer 1 fused attention -> hb (bf16)
  attn_l1<<<N_NODES, 256, 0, stream>>>(qkv1, s1, offsets, csr_src, hb);

  // layer 2 projections (skip -> s2 in ws; d_out stays write-only)
  gemm_mfma<__hip_bfloat16><<<dim3(768 / GBN, MBLK), 256, 0, stream>>>(
      hb, Wt2, b2, qkv2, N_NODES, 768, 512);
  gemm_mfma<float><<<dim3(128 / GBN, MBLK), 256, 0, stream>>>(
      hb, Wst2, bs2, s2, N_NODES, 128, 512);

  // layer 2 fused attention (mean over 2 heads): out = s2 + 0.5*sum (pure write)
  attn_l2<<<(N_NODES + 3) / 4, 256, 0, stream>>>(qkv2, s2, offsets, csr_src, out);
}

// Round 15
// 327.380 us; speedup vs baseline: 2.2050x; 1.2116x over previous
//
#include <hip/hip_runtime.h>
#include <hip/hip_bf16.h>
#include <math.h>

#define N_NODES 10000
#define N_EDGES 160000
// layer1: H=4, C=128 (concat -> 512); layer2: H=2, C=128 (mean -> 128)

typedef short v8s __attribute__((ext_vector_type(8)));
typedef short v4s __attribute__((ext_vector_type(4)));
typedef float v4f __attribute__((ext_vector_type(4)));

__device__ __forceinline__ float bf2f(short s) {
  union { unsigned u; float f; } c;
  c.u = ((unsigned)(unsigned short)s) << 16;
  return c.f;
}

// ---------------------------------------------------------------- CSR build
__global__ void zero_kernel(int* __restrict__ counts) {
  int i = blockIdx.x * 256 + threadIdx.x;
  if (i < N_NODES) counts[i] = 0;
}

__global__ void count_kernel(const int* __restrict__ dst, int* __restrict__ counts) {
  int e = blockIdx.x * 256 + threadIdx.x;
  if (e < N_EDGES) atomicAdd(&counts[dst[e]], 1);
}

// single block; wave-shuffle scan (3 barriers/chunk vs 16 for LDS ladder)
__global__ void scan_kernel(const int* __restrict__ counts, int* __restrict__ offsets,
                            int* __restrict__ cursor) {
  __shared__ int wsum[4];
  __shared__ int carry_s;
  int t = threadIdx.x;
  int lane = t & 63, wid = t >> 6;
  if (t == 0) carry_s = 0;
  __syncthreads();
  for (int base = 0; base < N_NODES; base += 256) {
    int i = base + t;
    int val = (i < N_NODES) ? counts[i] : 0;
    int x = val;
#pragma unroll
    for (int o = 1; o < 64; o <<= 1) {
      int y = __shfl_up(x, o);
      if (lane >= o) x += y;
    }
    if (lane == 63) wsum[wid] = x;
    __syncthreads();
    int woff = 0;
#pragma unroll
    for (int wq = 0; wq < 4; ++wq) woff += (wq < wid) ? wsum[wq] : 0;
    int chunk_total = wsum[0] + wsum[1] + wsum[2] + wsum[3];
    int excl = carry_s + woff + x - val;
    if (i < N_NODES) { offsets[i] = excl; cursor[i] = excl; }
    __syncthreads();
    if (t == 0) carry_s += chunk_total;
    __syncthreads();
  }
  if (t == 0) offsets[N_NODES] = carry_s;
}

__global__ void fill_kernel(const int* __restrict__ src, const int* __restrict__ dst,
                            int* __restrict__ cursor, int* __restrict__ csr_src) {
  int e = blockIdx.x * 256 + threadIdx.x;
  if (e < N_EDGES) {
    int slot = atomicAdd(&cursor[dst[e]], 1);
    csr_src[slot] = src[e];
  }
}

// ---------------------------------------------------------------- prep (bf16 convert + weight transpose-pack)
#define PREP_TOTAL (1280000 + 196608 + 65536 + 393216 + 65536 + 1536 + 768)
__global__ __launch_bounds__(256) void prep_kernel(
    const float* __restrict__ x,
    const float* __restrict__ Wq1, const float* __restrict__ Wk1,
    const float* __restrict__ Wv1, const float* __restrict__ Ws1,
    const float* __restrict__ Wq2, const float* __restrict__ Wk2,
    const float* __restrict__ Wv2, const float* __restrict__ Ws2,
    const float* __restrict__ bq1, const float* __restrict__ bk1,
    const float* __restrict__ bv1,
    const float* __restrict__ bq2, const float* __restrict__ bk2,
    const float* __restrict__ bv2,
    __hip_bfloat16* __restrict__ xb,
    __hip_bfloat16* __restrict__ Wt1, __hip_bfloat16* __restrict__ Wst1,
    __hip_bfloat16* __restrict__ Wt2, __hip_bfloat16* __restrict__ Wst2,
    float* __restrict__ b1, float* __restrict__ b2)
{
  int t = blockIdx.x * 256 + threadIdx.x;
  if (t >= PREP_TOTAL) return;
  if (t < 1280000) { xb[t] = __float2bfloat16(x[t]); return; }
  t -= 1280000;
  if (t < 196608) {                       // Wt1[n][k] = W[k][n], N=512 each, K=128
    int s = t / 65536, r = t % 65536;
    int n = r >> 7, k = r & 127;
    const float* W = (s == 0) ? Wq1 : (s == 1) ? Wk1 : Wv1;
    Wt1[(size_t)(s * 512 + n) * 128 + k] = __float2bfloat16(W[k * 512 + n]);
    return;
  }
  t -= 196608;
  if (t < 65536) {                        // Wst1 [512][128]
    int n = t >> 7, k = t & 127;
    Wst1[t] = __float2bfloat16(Ws1[k * 512 + n]);
    return;
  }
  t -= 65536;
  if (t < 393216) {                       // Wt2 [768][512], N=256 each, K=512
    int s = t / 131072, r = t % 131072;
    int n = r >> 9, k = r & 511;
    const float* W = (s == 0) ? Wq2 : (s == 1) ? Wk2 : Wv2;
    Wt2[(size_t)(s * 256 + n) * 512 + k] = __float2bfloat16(W[k * 256 + n]);
    return;
  }
  t -= 393216;
  if (t < 65536) {                        // Wst2 [128][512]
    int n = t >> 9, k = t & 511;
    Wst2[t] = __float2bfloat16(Ws2[k * 128 + n]);
    return;
  }
  t -= 65536;
  if (t < 1536) { b1[t] = (t < 512) ? bq1[t] : (t < 1024) ? bk1[t - 512] : bv1[t - 1024]; return; }
  t -= 1536;
  b2[t] = (t < 256) ? bq2[t] : (t < 512) ? bk2[t - 256] : bv2[t - 512];
}

// ---------------------------------------------------------------- bf16 MFMA GEMM
// C[M,N] = A[M,K](bf16,row-major) @ Bt[N,K](bf16 = B^T row-major) + bias.
// 128x128 tile, 4 waves (2x2), each wave 64x64 = 4x4 frags of 16x16x32.
#define GBM 128
#define GBN 128
#define GBK 32
#define LSTR 56

__device__ __forceinline__ void store_c(float* p, float v) { *p = v; }
__device__ __forceinline__ void store_c(__hip_bfloat16* p, float v) { *p = __float2bfloat16(v); }

template <typename OutT>
__global__ __launch_bounds__(256) void gemm_mfma(
    const __hip_bfloat16* __restrict__ A, const __hip_bfloat16* __restrict__ Bt,
    const float* __restrict__ bias, OutT* __restrict__ C,
    int M, int N, int K)
{
  __shared__ __hip_bfloat16 As[GBM][LSTR];
  __shared__ __hip_bfloat16 Bs[GBN][LSTR];
  const int tid = threadIdx.x;
  const int lane = tid & 63;
  const int w = tid >> 6;
  const int wm = (w >> 1) * 64, wn = (w & 1) * 64;
  const int row0 = blockIdx.y * GBM;
  const int col0 = blockIdx.x * GBN;

  v4f acc[4][4] = {};

  const int srow = tid >> 1;            // 0..127
  const int shalf = (tid & 1) * 16;     // bf16 elem offset: 0 or 16

  const int rA = lane & 15;
  const int kk = (lane >> 4) * 8;

  for (int k0 = 0; k0 < K; k0 += GBK) {
    {
      int gr = row0 + srow;
      v8s av0 = {}, av1 = {};
      if (gr < M) {
        const __hip_bfloat16* ap = A + (size_t)gr * K + k0 + shalf;
        av0 = *(const v8s*)ap;
        av1 = *(const v8s*)(ap + 8);
      }
      *(v8s*)&As[srow][shalf]     = av0;
      *(v8s*)&As[srow][shalf + 8] = av1;
      const __hip_bfloat16* bp = Bt + (size_t)(col0 + srow) * K + k0 + shalf;
      v8s bv0 = *(const v8s*)bp;
      v8s bv1 = *(const v8s*)(bp + 8);
      *(v8s*)&Bs[srow][shalf]     = bv0;
      *(v8s*)&Bs[srow][shalf + 8] = bv1;
    }
    __syncthreads();
    v8s af[4], bf[4];
#pragma unroll
    for (int i = 0; i < 4; ++i) {
      af[i] = *(const v8s*)&As[wm + i * 16 + rA][kk];
      bf[i] = *(const v8s*)&Bs[wn + i * 16 + rA][kk];
    }
#pragma unroll
    for (int i = 0; i < 4; ++i)
#pragma unroll
      for (int j = 0; j < 4; ++j)
        acc[i][j] = __builtin_amdgcn_mfma_f32_16x16x32_bf16(af[i], bf[j], acc[i][j], 0, 0, 0);
    __syncthreads();
  }

  // epilogue: C/D layout col = lane&15, row = (lane>>4)*4 + r   [m89 verified]
  const int cr = (lane >> 4) * 4;
  const int cc = lane & 15;
#pragma unroll
  for (int j = 0; j < 4; ++j) {
    int gcol = col0 + wn + j * 16 + cc;
    float bb = bias[gcol];
#pragma unroll
    for (int i = 0; i < 4; ++i) {
      int gr0 = row0 + wm + i * 16 + cr;
#pragma unroll
      for (int r = 0; r < 4; ++r) {
        int grow = gr0 + r;
        if (grow < M) store_c(&C[(size_t)grow * N + gcol], acc[i][j][r] + bb);
      }
    }
  }
}

// ---------------------------------------------------------------- fused attention (online softmax)
// layer1: ONE WAVE PER NODE, all 4 heads at once.
// qkv1 row = [q 512][k 512][v 512] bf16; 512 bf16 = 1024 B = 64 lanes x 16 B.
// lane l owns 8 elems of head l/16; dot = 4-step shfl_xor within 16-lane group.
__global__ __launch_bounds__(256) void attn_l1(
    const __hip_bfloat16* __restrict__ qkv, const float* __restrict__ s1,
    const int* __restrict__ offsets, const int* __restrict__ csr_src,
    __hip_bfloat16* __restrict__ hb)
{
  int n = blockIdx.x * 4 + (threadIdx.x >> 6);
  int lane = threadIdx.x & 63;
  if (n >= N_NODES) return;
  const float scale = 0.08838834764831845f;  // 1/sqrt(128)

  v8s qf = *(const v8s*)(qkv + (size_t)n * 1536 + lane * 8);
  float q[8];
#pragma unroll
  for (int i = 0; i < 8; ++i) q[i] = bf2f(qf[i]);

  int beg = offsets[n], end = offsets[n + 1];
  float m = -INFINITY, denom = 0.f;
  float acc[8] = {};
  for (int j = beg; j < end; ++j) {
    int s = csr_src[j];
    const __hip_bfloat16* base = qkv + (size_t)s * 1536 + lane * 8;
    v8s kf = *(const v8s*)(base + 512);
    v8s vf = *(const v8s*)(base + 1024);
    float p = 0.f;
#pragma unroll
    for (int i = 0; i < 8; ++i) p += q[i] * bf2f(kf[i]);
#pragma unroll
    for (int o = 1; o < 16; o <<= 1) p += __shfl_xor(p, o);   // reduce in head group
    p *= scale;
    float mn = fmaxf(m, p);
    float sc = __expf(m - mn);      // first iter: exp(-inf)=0
    float pe = __expf(p - mn);
    denom = denom * sc + pe;
#pragma unroll
    for (int i = 0; i < 8; ++i) acc[i] = acc[i] * sc + pe * bf2f(vf[i]);
    m = mn;
  }
  float inv = 1.f / (denom + 1e-16f);
  const float* sp = s1 + (size_t)n * 512 + lane * 8;
  __hip_bfloat16 ob[8];
#pragma unroll
  for (int i = 0; i < 8; ++i)
    ob[i] = __float2bfloat16(fmaxf(sp[i] + acc[i] * inv, 0.f));
  *(v8s*)(hb + (size_t)n * 512 + lane * 8) = *(v8s*)ob;
}

// layer2: ONE WAVE PER NODE, both heads at once. qkv2 row = [q 256][k 256][v 256].
// 256 bf16 = 512 B = 64 lanes x 8 B; lane l owns 4 elems of head l/32.
// Heads combined at end via shfl_xor(.,32); PURE WRITE out = s2 + 0.5*sum.
__global__ __launch_bounds__(256) void attn_l2(
    const __hip_bfloat16* __restrict__ qkv,
    const float* __restrict__ s2,
    const int* __restrict__ offsets, const int* __restrict__ csr_src,
    float* __restrict__ out)
{
  int n = blockIdx.x * 4 + (threadIdx.x >> 6);
  int lane = threadIdx.x & 63;
  if (n >= N_NODES) return;
  const float scale = 0.08838834764831845f;

  v4s qf = *(const v4s*)(qkv + (size_t)n * 768 + lane * 4);
  float q[4];
#pragma unroll
  for (int i = 0; i < 4; ++i) q[i] = bf2f(qf[i]);

  int beg = offsets[n], end = offsets[n + 1];
  float m = -INFINITY, denom = 0.f;
  float acc[4] = {};
  for (int j = beg; j < end; ++j) {
    int s = csr_src[j];
    const __hip_bfloat16* base = qkv + (size_t)s * 768 + lane * 4;
    v4s kf = *(const v4s*)(base + 256);
    v4s vf = *(const v4s*)(base + 512);
    float p = 0.f;
#pragma unroll
    for (int i = 0; i < 4; ++i) p += q[i] * bf2f(kf[i]);
#pragma unroll
    for (int o = 1; o < 32; o <<= 1) p += __shfl_xor(p, o);   // reduce in 32-lane head group
    p *= scale;
    float mn = fmaxf(m, p);
    float sc = __expf(m - mn);
    float pe = __expf(p - mn);
    denom = denom * sc + pe;
#pragma unroll
    for (int i = 0; i < 4; ++i) acc[i] = acc[i] * sc + pe * bf2f(vf[i]);
    m = mn;
  }
  float inv = 1.f / (denom + 1e-16f);
  float r[4];
#pragma unroll
  for (int i = 0; i < 4; ++i) {
    float mine = acc[i] * inv;
    r[i] = mine + __shfl_xor(mine, 32);   // add other head's value (same component)
  }
  if (lane < 32) {
    const float* sp2 = s2 + (size_t)n * 128 + lane * 4;
    float* op = out + (size_t)n * 128 + lane * 4;
    float4 ov;
    ov.x = sp2[0] + 0.5f * r[0];
    ov.y = sp2[1] + 0.5f * r[1];
    ov.z = sp2[2] + 0.5f * r[2];
    ov.w = sp2[3] + 0.5f * r[3];
    *(float4*)op = ov;
  }
}

// ---------------------------------------------------------------- launch
extern "C" void kernel_launch(void* const* d_in, const int* in_sizes, int n_in,
                              void* d_out, int out_size, void* d_ws, size_t ws_size,
                              hipStream_t stream) {
  const float* x   = (const float*)d_in[0];
  const int*   ei  = (const int*)d_in[1];
  const float* Wq1 = (const float*)d_in[2];  const float* bq1 = (const float*)d_in[3];
  const float* Wk1 = (const float*)d_in[4];  const float* bk1 = (const float*)d_in[5];
  const float* Wv1 = (const float*)d_in[6];  const float* bv1 = (const float*)d_in[7];
  const float* Ws1 = (const float*)d_in[8];  const float* bs1 = (const float*)d_in[9];
  const float* Wq2 = (const float*)d_in[10]; const float* bq2 = (const float*)d_in[11];
  const float* Wk2 = (const float*)d_in[12]; const float* bk2 = (const float*)d_in[13];
  const float* Wv2 = (const float*)d_in[14]; const float* bv2 = (const float*)d_in[15];
  const float* Ws2 = (const float*)d_in[16]; const float* bs2 = (const float*)d_in[17];
  float* out = (float*)d_out;

  const int* src = ei;
  const int* dst = ei + N_EDGES;

  char* ws = (char*)d_ws;
  size_t off = 0;
  auto take = [&](size_t bytes) -> void* {
    void* p = ws + off;
    off = (off + bytes + 255) & ~(size_t)255;
    return p;
  };
  int* counts  = (int*)take(N_NODES * 4);
  int* offsets = (int*)take((N_NODES + 1) * 4);
  int* cursor  = (int*)take(N_NODES * 4);
  int* csr_src = (int*)take(N_EDGES * 4);
  __hip_bfloat16* xb   = (__hip_bfloat16*)take((size_t)N_NODES * 128 * 2);
  __hip_bfloat16* Wt1  = (__hip_bfloat16*)take((size_t)1536 * 128 * 2);
  __hip_bfloat16* Wst1 = (__hip_bfloat16*)take((size_t)512 * 128 * 2);
  __hip_bfloat16* Wt2  = (__hip_bfloat16*)take((size_t)768 * 512 * 2);
  __hip_bfloat16* Wst2 = (__hip_bfloat16*)take((size_t)128 * 512 * 2);
  float* b1 = (float*)take(1536 * 4);
  float* b2 = (float*)take(768 * 4);
  __hip_bfloat16* qkv1 = (__hip_bfloat16*)take((size_t)N_NODES * 1536 * 2);
  float*          s1   = (float*)take((size_t)N_NODES * 512 * 4);
  __hip_bfloat16* hb   = (__hip_bfloat16*)take((size_t)N_NODES * 512 * 2);
  __hip_bfloat16* qkv2 = (__hip_bfloat16*)take((size_t)N_NODES * 768 * 2);
  float*          s2   = (float*)take((size_t)N_NODES * 128 * 4);
  (void)ws_size;  // ~87 MB

  // CSR by dst (all kernel dispatches; no memset nodes in the graph)
  zero_kernel<<<(N_NODES + 255) / 256, 256, 0, stream>>>(counts);
  count_kernel<<<(N_EDGES + 255) / 256, 256, 0, stream>>>(dst, counts);
  scan_kernel<<<1, 256, 0, stream>>>(counts, offsets, cursor);
  fill_kernel<<<(N_EDGES + 255) / 256, 256, 0, stream>>>(src, dst, cursor, csr_src);

  // bf16 conversion + weight transpose-pack (one kernel)
  prep_kernel<<<(PREP_TOTAL + 255) / 256, 256, 0, stream>>>(
      x, Wq1, Wk1, Wv1, Ws1, Wq2, Wk2, Wv2, Ws2,
      bq1, bk1, bv1, bq2, bk2, bv2,
      xb, Wt1, Wst1, Wt2, Wst2, b1, b2);

  const int MBLK = (N_NODES + GBM - 1) / GBM;  // 79

  // layer 1 projections: qkv (bf16 out) + skip s1 (fp32 out)
  gemm_mfma<__hip_bfloat16><<<dim3(1536 / GBN, MBLK), 256, 0, stream>>>(
      xb, Wt1, b1, qkv1, N_NODES, 1536, 128);
  gemm_mfma<float><<<dim3(512 / GBN, MBLK), 256, 0, stream>>>(
      xb, Wst1, bs1, s1, N_NODES, 512, 128);

  // layer 1 fused attention -> hb (bf16), one wave per node
  attn_l1<<<(N_NODES + 3) / 4, 256, 0, stream>>>(qkv1, s1, offsets, csr_src, hb);

  // layer 2 projections (skip -> s2 in ws; d_out stays write-only)
  gemm_mfma<__hip_bfloat16><<<dim3(768 / GBN, MBLK), 256, 0, stream>>>(
      hb, Wt2, b2, qkv2, N_NODES, 768, 512);
  gemm_mfma<float><<<dim3(128 / GBN, MBLK), 256, 0, stream>>>(
      hb, Wst2, bs2, s2, N_NODES, 128, 512);

  // layer 2 fused attention (mean over 2 heads): out = s2 + 0.5*sum (pure write)
  attn_l2<<<(N_NODES + 3) / 4, 256, 0, stream>>>(qkv2, s2, offsets, csr_src, out);
}

// Round 16
// 307.958 us; speedup vs baseline: 2.3441x; 1.0631x over previous
//
#include <hip/hip_runtime.h>
#include <hip/hip_bf16.h>
#include <math.h>

#define N_NODES 10000
#define N_EDGES 160000
// layer1: H=4, C=128 (concat -> 512); layer2: H=2, C=128 (mean -> 128)

typedef short v8s __attribute__((ext_vector_type(8)));
typedef short v4s __attribute__((ext_vector_type(4)));
typedef float v4f __attribute__((ext_vector_type(4)));

__device__ __forceinline__ float bf2f(short s) {
  union { unsigned u; float f; } c;
  c.u = ((unsigned)(unsigned short)s) << 16;
  return c.f;
}

// ---------------------------------------------------------------- CSR build
__global__ void zero_kernel(int* __restrict__ counts) {
  int i = blockIdx.x * 256 + threadIdx.x;
  if (i < N_NODES) counts[i] = 0;
}

__global__ void count_kernel(const int* __restrict__ dst, int* __restrict__ counts) {
  int e = blockIdx.x * 256 + threadIdx.x;
  if (e < N_EDGES) atomicAdd(&counts[dst[e]], 1);
}

// single block; wave-shuffle scan
__global__ void scan_kernel(const int* __restrict__ counts, int* __restrict__ offsets,
                            int* __restrict__ cursor) {
  __shared__ int wsum[4];
  __shared__ int carry_s;
  int t = threadIdx.x;
  int lane = t & 63, wid = t >> 6;
  if (t == 0) carry_s = 0;
  __syncthreads();
  for (int base = 0; base < N_NODES; base += 256) {
    int i = base + t;
    int val = (i < N_NODES) ? counts[i] : 0;
    int x = val;
#pragma unroll
    for (int o = 1; o < 64; o <<= 1) {
      int y = __shfl_up(x, o);
      if (lane >= o) x += y;
    }
    if (lane == 63) wsum[wid] = x;
    __syncthreads();
    int woff = 0;
#pragma unroll
    for (int wq = 0; wq < 4; ++wq) woff += (wq < wid) ? wsum[wq] : 0;
    int chunk_total = wsum[0] + wsum[1] + wsum[2] + wsum[3];
    int excl = carry_s + woff + x - val;
    if (i < N_NODES) { offsets[i] = excl; cursor[i] = excl; }
    __syncthreads();
    if (t == 0) carry_s += chunk_total;
    __syncthreads();
  }
  if (t == 0) offsets[N_NODES] = carry_s;
}

__global__ void fill_kernel(const int* __restrict__ src, const int* __restrict__ dst,
                            int* __restrict__ cursor, int* __restrict__ csr_src) {
  int e = blockIdx.x * 256 + threadIdx.x;
  if (e < N_EDGES) {
    int slot = atomicAdd(&cursor[dst[e]], 1);
    csr_src[slot] = src[e];
  }
}

// ---------------------------------------------------------------- prep (bf16 convert + weight transpose-pack)
#define PREP_TOTAL (1280000 + 196608 + 65536 + 393216 + 65536 + 1536 + 768)
__global__ __launch_bounds__(256) void prep_kernel(
    const float* __restrict__ x,
    const float* __restrict__ Wq1, const float* __restrict__ Wk1,
    const float* __restrict__ Wv1, const float* __restrict__ Ws1,
    const float* __restrict__ Wq2, const float* __restrict__ Wk2,
    const float* __restrict__ Wv2, const float* __restrict__ Ws2,
    const float* __restrict__ bq1, const float* __restrict__ bk1,
    const float* __restrict__ bv1,
    const float* __restrict__ bq2, const float* __restrict__ bk2,
    const float* __restrict__ bv2,
    __hip_bfloat16* __restrict__ xb,
    __hip_bfloat16* __restrict__ Wt1, __hip_bfloat16* __restrict__ Wst1,
    __hip_bfloat16* __restrict__ Wt2, __hip_bfloat16* __restrict__ Wst2,
    float* __restrict__ b1, float* __restrict__ b2)
{
  int t = blockIdx.x * 256 + threadIdx.x;
  if (t >= PREP_TOTAL) return;
  if (t < 1280000) { xb[t] = __float2bfloat16(x[t]); return; }
  t -= 1280000;
  if (t < 196608) {                       // Wt1[n][k] = W[k][n], N=512 each, K=128
    int s = t / 65536, r = t % 65536;
    int n = r >> 7, k = r & 127;
    const float* W = (s == 0) ? Wq1 : (s == 1) ? Wk1 : Wv1;
    Wt1[(size_t)(s * 512 + n) * 128 + k] = __float2bfloat16(W[k * 512 + n]);
    return;
  }
  t -= 196608;
  if (t < 65536) {                        // Wst1 [512][128]
    int n = t >> 7, k = t & 127;
    Wst1[t] = __float2bfloat16(Ws1[k * 512 + n]);
    return;
  }
  t -= 65536;
  if (t < 393216) {                       // Wt2 [768][512], N=256 each, K=512
    int s = t / 131072, r = t % 131072;
    int n = r >> 9, k = r & 511;
    const float* W = (s == 0) ? Wq2 : (s == 1) ? Wk2 : Wv2;
    Wt2[(size_t)(s * 256 + n) * 512 + k] = __float2bfloat16(W[k * 256 + n]);
    return;
  }
  t -= 393216;
  if (t < 65536) {                        // Wst2 [128][512]
    int n = t >> 9, k = t & 511;
    Wst2[t] = __float2bfloat16(Ws2[k * 128 + n]);
    return;
  }
  t -= 65536;
  if (t < 1536) { b1[t] = (t < 512) ? bq1[t] : (t < 1024) ? bk1[t - 512] : bv1[t - 1024]; return; }
  t -= 1536;
  b2[t] = (t < 256) ? bq2[t] : (t < 512) ? bk2[t - 256] : bv2[t - 512];
}

// ---------------------------------------------------------------- bf16 MFMA GEMM
// C[M,N] = A[M,K](bf16,row-major) @ Bt[N,K](bf16 = B^T row-major) + bias.
// 128x128 tile, 4 waves (2x2), each wave 64x64 = 4x4 frags of 16x16x32.
#define GBM 128
#define GBN 128
#define GBK 32
#define LSTR 56

__device__ __forceinline__ void store_c(float* p, float v) { *p = v; }
__device__ __forceinline__ void store_c(__hip_bfloat16* p, float v) { *p = __float2bfloat16(v); }

template <typename OutT>
__global__ __launch_bounds__(256) void gemm_mfma(
    const __hip_bfloat16* __restrict__ A, const __hip_bfloat16* __restrict__ Bt,
    const float* __restrict__ bias, OutT* __restrict__ C,
    int M, int N, int K)
{
  __shared__ __hip_bfloat16 As[GBM][LSTR];
  __shared__ __hip_bfloat16 Bs[GBN][LSTR];
  const int tid = threadIdx.x;
  const int lane = tid & 63;
  const int w = tid >> 6;
  const int wm = (w >> 1) * 64, wn = (w & 1) * 64;
  const int row0 = blockIdx.y * GBM;
  const int col0 = blockIdx.x * GBN;

  v4f acc[4][4] = {};

  const int srow = tid >> 1;            // 0..127
  const int shalf = (tid & 1) * 16;     // bf16 elem offset: 0 or 16

  const int rA = lane & 15;
  const int kk = (lane >> 4) * 8;

  for (int k0 = 0; k0 < K; k0 += GBK) {
    {
      int gr = row0 + srow;
      v8s av0 = {}, av1 = {};
      if (gr < M) {
        const __hip_bfloat16* ap = A + (size_t)gr * K + k0 + shalf;
        av0 = *(const v8s*)ap;
        av1 = *(const v8s*)(ap + 8);
      }
      *(v8s*)&As[srow][shalf]     = av0;
      *(v8s*)&As[srow][shalf + 8] = av1;
      const __hip_bfloat16* bp = Bt + (size_t)(col0 + srow) * K + k0 + shalf;
      v8s bv0 = *(const v8s*)bp;
      v8s bv1 = *(const v8s*)(bp + 8);
      *(v8s*)&Bs[srow][shalf]     = bv0;
      *(v8s*)&Bs[srow][shalf + 8] = bv1;
    }
    __syncthreads();
    v8s af[4], bf[4];
#pragma unroll
    for (int i = 0; i < 4; ++i) {
      af[i] = *(const v8s*)&As[wm + i * 16 + rA][kk];
      bf[i] = *(const v8s*)&Bs[wn + i * 16 + rA][kk];
    }
#pragma unroll
    for (int i = 0; i < 4; ++i)
#pragma unroll
      for (int j = 0; j < 4; ++j)
        acc[i][j] = __builtin_amdgcn_mfma_f32_16x16x32_bf16(af[i], bf[j], acc[i][j], 0, 0, 0);
    __syncthreads();
  }

  // epilogue: C/D layout col = lane&15, row = (lane>>4)*4 + r   [m89 verified]
  const int cr = (lane >> 4) * 4;
  const int cc = lane & 15;
#pragma unroll
  for (int j = 0; j < 4; ++j) {
    int gcol = col0 + wn + j * 16 + cc;
    float bb = bias[gcol];
#pragma unroll
    for (int i = 0; i < 4; ++i) {
      int gr0 = row0 + wm + i * 16 + cr;
#pragma unroll
      for (int r = 0; r < 4; ++r) {
        int grow = gr0 + r;
        if (grow < M) store_c(&C[(size_t)grow * N + gcol], acc[i][j][r] + bb);
      }
    }
  }
}

// ---------------------------------------------------------------- fused attention (online softmax)
// layer1: ONE WAVE PER NODE, 4 heads at once; lane owns 8 bf16 of head lane/16.
// Latency fix (r15 counters: VALU 30%, HBM 35% -> latency-bound):
//  (a) edge indices pre-loaded 64-wide, broadcast by __shfl (no per-edge index load)
//  (b) unroll-2 pairwise online-softmax: 4 gathers in flight per iteration.
__global__ __launch_bounds__(256) void attn_l1(
    const __hip_bfloat16* __restrict__ qkv, const float* __restrict__ s1,
    const int* __restrict__ offsets, const int* __restrict__ csr_src,
    __hip_bfloat16* __restrict__ hb)
{
  int n = blockIdx.x * 4 + (threadIdx.x >> 6);
  int lane = threadIdx.x & 63;
  if (n >= N_NODES) return;
  const float scale = 0.08838834764831845f;  // 1/sqrt(128)

  v8s qf = *(const v8s*)(qkv + (size_t)n * 1536 + lane * 8);
  float q[8];
#pragma unroll
  for (int i = 0; i < 8; ++i) q[i] = bf2f(qf[i]) * scale;   // pre-scaled

  int beg = offsets[n], end = offsets[n + 1];
  float m = -INFINITY, denom = 0.f;
  float acc[8] = {};

  for (int cbeg = beg; cbeg < end; cbeg += 64) {
    int cnt = end - cbeg; if (cnt > 64) cnt = 64;
    int myidx = (lane < cnt) ? csr_src[cbeg + lane] : 0;
    int j = 0;
    for (; j + 1 < cnt; j += 2) {
      int s0 = __shfl(myidx, j);
      int s1i = __shfl(myidx, j + 1);
      const __hip_bfloat16* b0 = qkv + (size_t)s0 * 1536 + lane * 8;
      const __hip_bfloat16* b1 = qkv + (size_t)s1i * 1536 + lane * 8;
      v8s k0 = *(const v8s*)(b0 + 512);
      v8s v0 = *(const v8s*)(b0 + 1024);
      v8s k1 = *(const v8s*)(b1 + 512);
      v8s v1 = *(const v8s*)(b1 + 1024);
      float p0 = 0.f, p1 = 0.f;
#pragma unroll
      for (int i = 0; i < 8; ++i) { p0 += q[i] * bf2f(k0[i]); p1 += q[i] * bf2f(k1[i]); }
#pragma unroll
      for (int o = 1; o < 16; o <<= 1) { p0 += __shfl_xor(p0, o); p1 += __shfl_xor(p1, o); }
      float mn = fmaxf(m, fmaxf(p0, p1));
      float sc  = __expf(m - mn);       // first iter: exp(-inf)=0
      float pe0 = __expf(p0 - mn);
      float pe1 = __expf(p1 - mn);
      denom = denom * sc + pe0 + pe1;
#pragma unroll
      for (int i = 0; i < 8; ++i)
        acc[i] = acc[i] * sc + pe0 * bf2f(v0[i]) + pe1 * bf2f(v1[i]);
      m = mn;
    }
    if (j < cnt) {
      int s0 = __shfl(myidx, j);
      const __hip_bfloat16* b0 = qkv + (size_t)s0 * 1536 + lane * 8;
      v8s k0 = *(const v8s*)(b0 + 512);
      v8s v0 = *(const v8s*)(b0 + 1024);
      float p0 = 0.f;
#pragma unroll
      for (int i = 0; i < 8; ++i) p0 += q[i] * bf2f(k0[i]);
#pragma unroll
      for (int o = 1; o < 16; o <<= 1) p0 += __shfl_xor(p0, o);
      float mn = fmaxf(m, p0);
      float sc  = __expf(m - mn);
      float pe0 = __expf(p0 - mn);
      denom = denom * sc + pe0;
#pragma unroll
      for (int i = 0; i < 8; ++i) acc[i] = acc[i] * sc + pe0 * bf2f(v0[i]);
      m = mn;
    }
  }
  float inv = 1.f / (denom + 1e-16f);
  const float* sp = s1 + (size_t)n * 512 + lane * 8;
  __hip_bfloat16 ob[8];
#pragma unroll
  for (int i = 0; i < 8; ++i)
    ob[i] = __float2bfloat16(fmaxf(sp[i] + acc[i] * inv, 0.f));
  *(v8s*)(hb + (size_t)n * 512 + lane * 8) = *(v8s*)ob;
}

// layer2: ONE WAVE PER NODE, both heads; lane owns 4 bf16 of head lane/32.
// Same latency fixes; heads combined via shfl_xor(.,32); PURE WRITE to out.
__global__ __launch_bounds__(256) void attn_l2(
    const __hip_bfloat16* __restrict__ qkv,
    const float* __restrict__ s2,
    const int* __restrict__ offsets, const int* __restrict__ csr_src,
    float* __restrict__ out)
{
  int n = blockIdx.x * 4 + (threadIdx.x >> 6);
  int lane = threadIdx.x & 63;
  if (n >= N_NODES) return;
  const float scale = 0.08838834764831845f;

  v4s qf = *(const v4s*)(qkv + (size_t)n * 768 + lane * 4);
  float q[4];
#pragma unroll
  for (int i = 0; i < 4; ++i) q[i] = bf2f(qf[i]) * scale;

  int beg = offsets[n], end = offsets[n + 1];
  float m = -INFINITY, denom = 0.f;
  float acc[4] = {};

  for (int cbeg = beg; cbeg < end; cbeg += 64) {
    int cnt = end - cbeg; if (cnt > 64) cnt = 64;
    int myidx = (lane < cnt) ? csr_src[cbeg + lane] : 0;
    int j = 0;
    for (; j + 1 < cnt; j += 2) {
      int s0 = __shfl(myidx, j);
      int s1i = __shfl(myidx, j + 1);
      const __hip_bfloat16* b0 = qkv + (size_t)s0 * 768 + lane * 4;
      const __hip_bfloat16* b1 = qkv + (size_t)s1i * 768 + lane * 4;
      v4s k0 = *(const v4s*)(b0 + 256);
      v4s v0 = *(const v4s*)(b0 + 512);
      v4s k1 = *(const v4s*)(b1 + 256);
      v4s v1 = *(const v4s*)(b1 + 512);
      float p0 = 0.f, p1 = 0.f;
#pragma unroll
      for (int i = 0; i < 4; ++i) { p0 += q[i] * bf2f(k0[i]); p1 += q[i] * bf2f(k1[i]); }
#pragma unroll
      for (int o = 1; o < 32; o <<= 1) { p0 += __shfl_xor(p0, o); p1 += __shfl_xor(p1, o); }
      float mn = fmaxf(m, fmaxf(p0, p1));
      float sc  = __expf(m - mn);
      float pe0 = __expf(p0 - mn);
      float pe1 = __expf(p1 - mn);
      denom = denom * sc + pe0 + pe1;
#pragma unroll
      for (int i = 0; i < 4; ++i)
        acc[i] = acc[i] * sc + pe0 * bf2f(v0[i]) + pe1 * bf2f(v1[i]);
      m = mn;
    }
    if (j < cnt) {
      int s0 = __shfl(myidx, j);
      const __hip_bfloat16* b0 = qkv + (size_t)s0 * 768 + lane * 4;
      v4s k0 = *(const v4s*)(b0 + 256);
      v4s v0 = *(const v4s*)(b0 + 512);
      float p0 = 0.f;
#pragma unroll
      for (int i = 0; i < 4; ++i) p0 += q[i] * bf2f(k0[i]);
#pragma unroll
      for (int o = 1; o < 32; o <<= 1) p0 += __shfl_xor(p0, o);
      float mn = fmaxf(m, p0);
      float sc  = __expf(m - mn);
      float pe0 = __expf(p0 - mn);
      denom = denom * sc + pe0;
#pragma unroll
      for (int i = 0; i < 4; ++i) acc[i] = acc[i] * sc + pe0 * bf2f(v0[i]);
      m = mn;
    }
  }
  float inv = 1.f / (denom + 1e-16f);
  float r[4];
#pragma unroll
  for (int i = 0; i < 4; ++i) {
    float mine = acc[i] * inv;
    r[i] = mine + __shfl_xor(mine, 32);   // add other head's same component
  }
  if (lane < 32) {
    const float* sp2 = s2 + (size_t)n * 128 + lane * 4;
    float* op = out + (size_t)n * 128 + lane * 4;
    float4 ov;
    ov.x = sp2[0] + 0.5f * r[0];
    ov.y = sp2[1] + 0.5f * r[1];
    ov.z = sp2[2] + 0.5f * r[2];
    ov.w = sp2[3] + 0.5f * r[3];
    *(float4*)op = ov;
  }
}

// ---------------------------------------------------------------- launch
extern "C" void kernel_launch(void* const* d_in, const int* in_sizes, int n_in,
                              void* d_out, int out_size, void* d_ws, size_t ws_size,
                              hipStream_t stream) {
  const float* x   = (const float*)d_in[0];
  const int*   ei  = (const int*)d_in[1];
  const float* Wq1 = (const float*)d_in[2];  const float* bq1 = (const float*)d_in[3];
  const float* Wk1 = (const float*)d_in[4];  const float* bk1 = (const float*)d_in[5];
  const float* Wv1 = (const float*)d_in[6];  const float* bv1 = (const float*)d_in[7];
  const float* Ws1 = (const float*)d_in[8];  const float* bs1 = (const float*)d_in[9];
  const float* Wq2 = (const float*)d_in[10]; const float* bq2 = (const float*)d_in[11];
  const float* Wk2 = (const float*)d_in[12]; const float* bk2 = (const float*)d_in[13];
  const float* Wv2 = (const float*)d_in[14]; const float* bv2 = (const float*)d_in[15];
  const float* Ws2 = (const float*)d_in[16]; const float* bs2 = (const float*)d_in[17];
  float* out = (float*)d_out;

  const int* src = ei;
  const int* dst = ei + N_EDGES;

  char* ws = (char*)d_ws;
  size_t off = 0;
  auto take = [&](size_t bytes) -> void* {
    void* p = ws + off;
    off = (off + bytes + 255) & ~(size_t)255;
    return p;
  };
  int* counts  = (int*)take(N_NODES * 4);
  int* offsets = (int*)take((N_NODES + 1) * 4);
  int* cursor  = (int*)take(N_NODES * 4);
  int* csr_src = (int*)take(N_EDGES * 4);
  __hip_bfloat16* xb   = (__hip_bfloat16*)take((size_t)N_NODES * 128 * 2);
  __hip_bfloat16* Wt1  = (__hip_bfloat16*)take((size_t)1536 * 128 * 2);
  __hip_bfloat16* Wst1 = (__hip_bfloat16*)take((size_t)512 * 128 * 2);
  __hip_bfloat16* Wt2  = (__hip_bfloat16*)take((size_t)768 * 512 * 2);
  __hip_bfloat16* Wst2 = (__hip_bfloat16*)take((size_t)128 * 512 * 2);
  float* b1 = (float*)take(1536 * 4);
  float* b2 = (float*)take(768 * 4);
  __hip_bfloat16* qkv1 = (__hip_bfloat16*)take((size_t)N_NODES * 1536 * 2);
  float*          s1   = (float*)take((size_t)N_NODES * 512 * 4);
  __hip_bfloat16* hb   = (__hip_bfloat16*)take((size_t)N_NODES * 512 * 2);
  __hip_bfloat16* qkv2 = (__hip_bfloat16*)take((size_t)N_NODES * 768 * 2);
  float*          s2   = (float*)take((size_t)N_NODES * 128 * 4);
  (void)ws_size;  // ~87 MB

  // CSR by dst (all kernel dispatches; no memset nodes in the graph)
  zero_kernel<<<(N_NODES + 255) / 256, 256, 0, stream>>>(counts);
  count_kernel<<<(N_EDGES + 255) / 256, 256, 0, stream>>>(dst, counts);
  scan_kernel<<<1, 256, 0, stream>>>(counts, offsets, cursor);
  fill_kernel<<<(N_EDGES + 255) / 256, 256, 0, stream>>>(src, dst, cursor, csr_src);

  // bf16 conversion + weight transpose-pack (one kernel)
  prep_kernel<<<(PREP_TOTAL + 255) / 256, 256, 0, stream>>>(
      x, Wq1, Wk1, Wv1, Ws1, Wq2, Wk2, Wv2, Ws2,
      bq1, bk1, bv1, bq2, bk2, bv2,
      xb, Wt1, Wst1, Wt2, Wst2, b1, b2);

  const int MBLK = (N_NODES + GBM - 1) / GBM;  // 79

  // layer 1 projections: qkv (bf16 out) + skip s1 (fp32 out)
  gemm_mfma<__hip_bfloat16><<<dim3(1536 / GBN, MBLK), 256, 0, stream>>>(
      xb, Wt1, b1, qkv1, N_NODES, 1536, 128);
  gemm_mfma<float><<<dim3(512 / GBN, MBLK), 256, 0, stream>>>(
      xb, Wst1, bs1, s1, N_NODES, 512, 128);

  // layer 1 fused attention -> hb (bf16), one wave per node
  attn_l1<<<(N_NODES + 3) / 4, 256, 0, stream>>>(qkv1, s1, offsets, csr_src, hb);

  // layer 2 projections (skip -> s2 in ws; d_out stays write-only)
  gemm_mfma<__hip_bfloat16><<<dim3(768 / GBN, MBLK), 256, 0, stream>>>(
      hb, Wt2, b2, qkv2, N_NODES, 768, 512);
  gemm_mfma<float><<<dim3(128 / GBN, MBLK), 256, 0, stream>>>(
      hb, Wst2, bs2, s2, N_NODES, 128, 512);

  // layer 2 fused attention (mean over 2 heads): out = s2 + 0.5*sum (pure write)
  attn_l2<<<(N_NODES + 3) / 4, 256, 0, stream>>>(qkv2, s2, offsets, csr_src, out);
}

// Round 17
// 283.208 us; speedup vs baseline: 2.5490x; 1.0874x over previous
//
#include <hip/hip_runtime.h>
#include <hip/hip_bf16.h>
#include <math.h>

#define N_NODES 10000
#define N_EDGES 160000
// layer1: H=4, C=128 (concat -> 512); layer2: H=2, C=128 (mean -> 128)

typedef short v8s __attribute__((ext_vector_type(8)));
typedef short v4s __attribute__((ext_vector_type(4)));
typedef float v4f __attribute__((ext_vector_type(4)));

__device__ __forceinline__ float bf2f(short s) {
  union { unsigned u; float f; } c;
  c.u = ((unsigned)(unsigned short)s) << 16;
  return c.f;
}

// ---------------------------------------------------------------- CSR build
__global__ void zero_kernel(int* __restrict__ counts) {
  int i = blockIdx.x * 256 + threadIdx.x;
  if (i < N_NODES) counts[i] = 0;
}

__global__ void count_kernel(const int* __restrict__ dst, int* __restrict__ counts) {
  int e = blockIdx.x * 256 + threadIdx.x;
  if (e < N_EDGES) atomicAdd(&counts[dst[e]], 1);
}

// single block; wave-shuffle scan
__global__ void scan_kernel(const int* __restrict__ counts, int* __restrict__ offsets,
                            int* __restrict__ cursor) {
  __shared__ int wsum[4];
  __shared__ int carry_s;
  int t = threadIdx.x;
  int lane = t & 63, wid = t >> 6;
  if (t == 0) carry_s = 0;
  __syncthreads();
  for (int base = 0; base < N_NODES; base += 256) {
    int i = base + t;
    int val = (i < N_NODES) ? counts[i] : 0;
    int x = val;
#pragma unroll
    for (int o = 1; o < 64; o <<= 1) {
      int y = __shfl_up(x, o);
      if (lane >= o) x += y;
    }
    if (lane == 63) wsum[wid] = x;
    __syncthreads();
    int woff = 0;
#pragma unroll
    for (int wq = 0; wq < 4; ++wq) woff += (wq < wid) ? wsum[wq] : 0;
    int chunk_total = wsum[0] + wsum[1] + wsum[2] + wsum[3];
    int excl = carry_s + woff + x - val;
    if (i < N_NODES) { offsets[i] = excl; cursor[i] = excl; }
    __syncthreads();
    if (t == 0) carry_s += chunk_total;
    __syncthreads();
  }
  if (t == 0) offsets[N_NODES] = carry_s;
}

__global__ void fill_kernel(const int* __restrict__ src, const int* __restrict__ dst,
                            int* __restrict__ cursor, int* __restrict__ csr_src) {
  int e = blockIdx.x * 256 + threadIdx.x;
  if (e < N_EDGES) {
    int slot = atomicAdd(&cursor[dst[e]], 1);
    csr_src[slot] = src[e];
  }
}

// ---------------------------------------------------------------- prep
// bf16 convert + weight transpose-pack. All transpose segments are remapped so
// consecutive threads step n (coalesced READS of W[k][n]); the scattered bf16
// writes are absorbed by L2 (r16 fix: old mapping had stride-512 fp32 reads).
// b1 = [bq1|bk1|bv1|bs1] (2048), b2 = [bq2|bk2|bv2|bs2] (896) for merged GEMMs.
#define PREP_TOTAL (1280000 + 196608 + 65536 + 393216 + 65536 + 2048 + 896)
__global__ __launch_bounds__(256) void prep_kernel(
    const float* __restrict__ x,
    const float* __restrict__ Wq1, const float* __restrict__ Wk1,
    const float* __restrict__ Wv1, const float* __restrict__ Ws1,
    const float* __restrict__ Wq2, const float* __restrict__ Wk2,
    const float* __restrict__ Wv2, const float* __restrict__ Ws2,
    const float* __restrict__ bq1, const float* __restrict__ bk1,
    const float* __restrict__ bv1, const float* __restrict__ bs1,
    const float* __restrict__ bq2, const float* __restrict__ bk2,
    const float* __restrict__ bv2, const float* __restrict__ bs2,
    __hip_bfloat16* __restrict__ xb,
    __hip_bfloat16* __restrict__ Wt1, __hip_bfloat16* __restrict__ Wst1,
    __hip_bfloat16* __restrict__ Wt2, __hip_bfloat16* __restrict__ Wst2,
    float* __restrict__ b1, float* __restrict__ b2)
{
  int t = blockIdx.x * 256 + threadIdx.x;
  if (t >= PREP_TOTAL) return;
  if (t < 1280000) { xb[t] = __float2bfloat16(x[t]); return; }
  t -= 1280000;
  if (t < 196608) {                       // Wt1[n][k] = W[k][n], N=512 each, K=128
    int s = t / 65536, r = t % 65536;
    int n = r & 511, k = r >> 9;          // lanes step n -> coalesced read
    const float* W = (s == 0) ? Wq1 : (s == 1) ? Wk1 : Wv1;
    Wt1[(size_t)(s * 512 + n) * 128 + k] = __float2bfloat16(W[k * 512 + n]);
    return;
  }
  t -= 196608;
  if (t < 65536) {                        // Wst1 [512][128]
    int n = t & 511, k = t >> 9;
    Wst1[(size_t)n * 128 + k] = __float2bfloat16(Ws1[k * 512 + n]);
    return;
  }
  t -= 65536;
  if (t < 393216) {                       // Wt2 [768][512], N=256 each, K=512
    int s = t / 131072, r = t % 131072;
    int n = r & 255, k = r >> 8;
    const float* W = (s == 0) ? Wq2 : (s == 1) ? Wk2 : Wv2;
    Wt2[(size_t)(s * 256 + n) * 512 + k] = __float2bfloat16(W[k * 256 + n]);
    return;
  }
  t -= 393216;
  if (t < 65536) {                        // Wst2 [128][512]
    int n = t & 127, k = t >> 7;
    Wst2[(size_t)n * 512 + k] = __float2bfloat16(Ws2[k * 128 + n]);
    return;
  }
  t -= 65536;
  if (t < 2048) {
    b1[t] = (t < 512) ? bq1[t] : (t < 1024) ? bk1[t - 512]
          : (t < 1536) ? bv1[t - 1024] : bs1[t - 1536];
    return;
  }
  t -= 2048;
  b2[t] = (t < 256) ? bq2[t] : (t < 512) ? bk2[t - 256]
        : (t < 768) ? bv2[t - 512] : bs2[t - 768];
}

// ---------------------------------------------------------------- bf16 MFMA GEMM (split output)
// C[M,Ntot] = A[M,K] @ Bt[Ntot,K] + bias. Columns [0,split) -> C1 (bf16,
// stride=split); [split,Ntot) -> C2 (fp32, stride=Ntot-split). split%128==0,
// so the choice is block-uniform. 128x128 tile, 4 waves, 16x16x32 MFMA.
#define GBM 128
#define GBN 128
#define GBK 32
#define LSTR 56

__global__ __launch_bounds__(256) void gemm_mfma_split(
    const __hip_bfloat16* __restrict__ A, const __hip_bfloat16* __restrict__ Bt,
    const float* __restrict__ bias,
    __hip_bfloat16* __restrict__ C1, float* __restrict__ C2,
    int M, int Ntot, int K, int split)
{
  __shared__ __hip_bfloat16 As[GBM][LSTR];
  __shared__ __hip_bfloat16 Bs[GBN][LSTR];
  const int tid = threadIdx.x;
  const int lane = tid & 63;
  const int w = tid >> 6;
  const int wm = (w >> 1) * 64, wn = (w & 1) * 64;
  const int row0 = blockIdx.y * GBM;
  const int col0 = blockIdx.x * GBN;

  v4f acc[4][4] = {};

  const int srow = tid >> 1;            // 0..127
  const int shalf = (tid & 1) * 16;     // bf16 elem offset: 0 or 16

  const int rA = lane & 15;
  const int kk = (lane >> 4) * 8;

  for (int k0 = 0; k0 < K; k0 += GBK) {
    {
      int gr = row0 + srow;
      v8s av0 = {}, av1 = {};
      if (gr < M) {
        const __hip_bfloat16* ap = A + (size_t)gr * K + k0 + shalf;
        av0 = *(const v8s*)ap;
        av1 = *(const v8s*)(ap + 8);
      }
      *(v8s*)&As[srow][shalf]     = av0;
      *(v8s*)&As[srow][shalf + 8] = av1;
      const __hip_bfloat16* bp = Bt + (size_t)(col0 + srow) * K + k0 + shalf;
      v8s bv0 = *(const v8s*)bp;
      v8s bv1 = *(const v8s*)(bp + 8);
      *(v8s*)&Bs[srow][shalf]     = bv0;
      *(v8s*)&Bs[srow][shalf + 8] = bv1;
    }
    __syncthreads();
    v8s af[4], bf[4];
#pragma unroll
    for (int i = 0; i < 4; ++i) {
      af[i] = *(const v8s*)&As[wm + i * 16 + rA][kk];
      bf[i] = *(const v8s*)&Bs[wn + i * 16 + rA][kk];
    }
#pragma unroll
    for (int i = 0; i < 4; ++i)
#pragma unroll
      for (int j = 0; j < 4; ++j)
        acc[i][j] = __builtin_amdgcn_mfma_f32_16x16x32_bf16(af[i], bf[j], acc[i][j], 0, 0, 0);
    __syncthreads();
  }

  // epilogue: C/D layout col = lane&15, row = (lane>>4)*4 + r   [m89 verified]
  const int cr = (lane >> 4) * 4;
  const int cc = lane & 15;
  const bool toC1 = (col0 < split);
  const int n2 = Ntot - split;
#pragma unroll
  for (int j = 0; j < 4; ++j) {
    int gcol = col0 + wn + j * 16 + cc;
    float bb = bias[gcol];
#pragma unroll
    for (int i = 0; i < 4; ++i) {
      int gr0 = row0 + wm + i * 16 + cr;
#pragma unroll
      for (int r = 0; r < 4; ++r) {
        int grow = gr0 + r;
        if (grow < M) {
          float v = acc[i][j][r] + bb;
          if (toC1) C1[(size_t)grow * split + gcol] = __float2bfloat16(v);
          else      C2[(size_t)grow * n2 + (gcol - split)] = v;
        }
      }
    }
  }
}

// ---------------------------------------------------------------- fused attention (online softmax)
// layer1: ONE WAVE PER NODE, 4 heads at once; lane owns 8 bf16 of head lane/16.
// r16 counters (VALU 26%, HBM 39%, occ 40%) -> still latency-bound; unroll-4:
// 8 gathers in flight per iteration, one rescale per 4 edges.
__global__ __launch_bounds__(256) void attn_l1(
    const __hip_bfloat16* __restrict__ qkv, const float* __restrict__ s1,
    const int* __restrict__ offsets, const int* __restrict__ csr_src,
    __hip_bfloat16* __restrict__ hb)
{
  int n = blockIdx.x * 4 + (threadIdx.x >> 6);
  int lane = threadIdx.x & 63;
  if (n >= N_NODES) return;
  const float scale = 0.08838834764831845f;  // 1/sqrt(128)

  v8s qf = *(const v8s*)(qkv + (size_t)n * 1536 + lane * 8);
  float q[8];
#pragma unroll
  for (int i = 0; i < 8; ++i) q[i] = bf2f(qf[i]) * scale;   // pre-scaled

  int beg = offsets[n], end = offsets[n + 1];
  float m = -INFINITY, denom = 0.f;
  float acc[8] = {};

  for (int cbeg = beg; cbeg < end; cbeg += 64) {
    int cnt = end - cbeg; if (cnt > 64) cnt = 64;
    int myidx = (lane < cnt) ? csr_src[cbeg + lane] : 0;
    int j = 0;
    for (; j + 3 < cnt; j += 4) {
      int s0 = __shfl(myidx, j);
      int s1i = __shfl(myidx, j + 1);
      int s2i = __shfl(myidx, j + 2);
      int s3i = __shfl(myidx, j + 3);
      const __hip_bfloat16* b0 = qkv + (size_t)s0 * 1536 + lane * 8;
      const __hip_bfloat16* b1 = qkv + (size_t)s1i * 1536 + lane * 8;
      const __hip_bfloat16* b2 = qkv + (size_t)s2i * 1536 + lane * 8;
      const __hip_bfloat16* b3 = qkv + (size_t)s3i * 1536 + lane * 8;
      v8s k0 = *(const v8s*)(b0 + 512);
      v8s v0 = *(const v8s*)(b0 + 1024);
      v8s k1 = *(const v8s*)(b1 + 512);
      v8s v1 = *(const v8s*)(b1 + 1024);
      v8s k2 = *(const v8s*)(b2 + 512);
      v8s v2 = *(const v8s*)(b2 + 1024);
      v8s k3 = *(const v8s*)(b3 + 512);
      v8s v3 = *(const v8s*)(b3 + 1024);
      float p0 = 0.f, p1 = 0.f, p2 = 0.f, p3 = 0.f;
#pragma unroll
      for (int i = 0; i < 8; ++i) {
        p0 += q[i] * bf2f(k0[i]); p1 += q[i] * bf2f(k1[i]);
        p2 += q[i] * bf2f(k2[i]); p3 += q[i] * bf2f(k3[i]);
      }
#pragma unroll
      for (int o = 1; o < 16; o <<= 1) {
        p0 += __shfl_xor(p0, o); p1 += __shfl_xor(p1, o);
        p2 += __shfl_xor(p2, o); p3 += __shfl_xor(p3, o);
      }
      float mn = fmaxf(fmaxf(m, fmaxf(p0, p1)), fmaxf(p2, p3));
      float sc  = __expf(m - mn);       // first iter: exp(-inf)=0
      float pe0 = __expf(p0 - mn);
      float pe1 = __expf(p1 - mn);
      float pe2 = __expf(p2 - mn);
      float pe3 = __expf(p3 - mn);
      denom = denom * sc + ((pe0 + pe1) + (pe2 + pe3));
#pragma unroll
      for (int i = 0; i < 8; ++i)
        acc[i] = acc[i] * sc + ((pe0 * bf2f(v0[i]) + pe1 * bf2f(v1[i]))
                              + (pe2 * bf2f(v2[i]) + pe3 * bf2f(v3[i])));
      m = mn;
    }
    for (; j < cnt; ++j) {
      int s0 = __shfl(myidx, j);
      const __hip_bfloat16* b0 = qkv + (size_t)s0 * 1536 + lane * 8;
      v8s k0 = *(const v8s*)(b0 + 512);
      v8s v0 = *(const v8s*)(b0 + 1024);
      float p0 = 0.f;
#pragma unroll
      for (int i = 0; i < 8; ++i) p0 += q[i] * bf2f(k0[i]);
#pragma unroll
      for (int o = 1; o < 16; o <<= 1) p0 += __shfl_xor(p0, o);
      float mn = fmaxf(m, p0);
      float sc  = __expf(m - mn);
      float pe0 = __expf(p0 - mn);
      denom = denom * sc + pe0;
#pragma unroll
      for (int i = 0; i < 8; ++i) acc[i] = acc[i] * sc + pe0 * bf2f(v0[i]);
      m = mn;
    }
  }
  float inv = 1.f / (denom + 1e-16f);
  const float* sp = s1 + (size_t)n * 512 + lane * 8;
  __hip_bfloat16 ob[8];
#pragma unroll
  for (int i = 0; i < 8; ++i)
    ob[i] = __float2bfloat16(fmaxf(sp[i] + acc[i] * inv, 0.f));
  *(v8s*)(hb + (size_t)n * 512 + lane * 8) = *(v8s*)ob;
}

// layer2: ONE WAVE PER NODE, both heads; lane owns 4 bf16 of head lane/32.
// unroll-4; heads combined via shfl_xor(.,32); PURE WRITE out = s2 + 0.5*sum.
__global__ __launch_bounds__(256) void attn_l2(
    const __hip_bfloat16* __restrict__ qkv,
    const float* __restrict__ s2,
    const int* __restrict__ offsets, const int* __restrict__ csr_src,
    float* __restrict__ out)
{
  int n = blockIdx.x * 4 + (threadIdx.x >> 6);
  int lane = threadIdx.x & 63;
  if (n >= N_NODES) return;
  const float scale = 0.08838834764831845f;

  v4s qf = *(const v4s*)(qkv + (size_t)n * 768 + lane * 4);
  float q[4];
#pragma unroll
  for (int i = 0; i < 4; ++i) q[i] = bf2f(qf[i]) * scale;

  int beg = offsets[n], end = offsets[n + 1];
  float m = -INFINITY, denom = 0.f;
  float acc[4] = {};

  for (int cbeg = beg; cbeg < end; cbeg += 64) {
    int cnt = end - cbeg; if (cnt > 64) cnt = 64;
    int myidx = (lane < cnt) ? csr_src[cbeg + lane] : 0;
    int j = 0;
    for (; j + 3 < cnt; j += 4) {
      int s0 = __shfl(myidx, j);
      int s1i = __shfl(myidx, j + 1);
      int s2i = __shfl(myidx, j + 2);
      int s3i = __shfl(myidx, j + 3);
      const __hip_bfloat16* b0 = qkv + (size_t)s0 * 768 + lane * 4;
      const __hip_bfloat16* b1 = qkv + (size_t)s1i * 768 + lane * 4;
      const __hip_bfloat16* b2 = qkv + (size_t)s2i * 768 + lane * 4;
      const __hip_bfloat16* b3 = qkv + (size_t)s3i * 768 + lane * 4;
      v4s k0 = *(const v4s*)(b0 + 256);
      v4s v0 = *(const v4s*)(b0 + 512);
      v4s k1 = *(const v4s*)(b1 + 256);
      v4s v1 = *(const v4s*)(b1 + 512);
      v4s k2 = *(const v4s*)(b2 + 256);
      v4s v2 = *(const v4s*)(b2 + 512);
      v4s k3 = *(const v4s*)(b3 + 256);
      v4s v3 = *(const v4s*)(b3 + 512);
      float p0 = 0.f, p1 = 0.f, p2 = 0.f, p3 = 0.f;
#pragma unroll
      for (int i = 0; i < 4; ++i) {
        p0 += q[i] * bf2f(k0[i]); p1 += q[i] * bf2f(k1[i]);
        p2 += q[i] * bf2f(k2[i]); p3 += q[i] * bf2f(k3[i]);
      }
#pragma unroll
      for (int o = 1; o < 32; o <<= 1) {
        p0 += __shfl_xor(p0, o); p1 += __shfl_xor(p1, o);
        p2 += __shfl_xor(p2, o); p3 += __shfl_xor(p3, o);
      }
      float mn = fmaxf(fmaxf(m, fmaxf(p0, p1)), fmaxf(p2, p3));
      float sc  = __expf(m - mn);
      float pe0 = __expf(p0 - mn);
      float pe1 = __expf(p1 - mn);
      float pe2 = __expf(p2 - mn);
      float pe3 = __expf(p3 - mn);
      denom = denom * sc + ((pe0 + pe1) + (pe2 + pe3));
#pragma unroll
      for (int i = 0; i < 4; ++i)
        acc[i] = acc[i] * sc + ((pe0 * bf2f(v0[i]) + pe1 * bf2f(v1[i]))
                              + (pe2 * bf2f(v2[i]) + pe3 * bf2f(v3[i])));
      m = mn;
    }
    for (; j < cnt; ++j) {
      int s0 = __shfl(myidx, j);
      const __hip_bfloat16* b0 = qkv + (size_t)s0 * 768 + lane * 4;
      v4s k0 = *(const v4s*)(b0 + 256);
      v4s v0 = *(const v4s*)(b0 + 512);
      float p0 = 0.f;
#pragma unroll
      for (int i = 0; i < 4; ++i) p0 += q[i] * bf2f(k0[i]);
#pragma unroll
      for (int o = 1; o < 32; o <<= 1) p0 += __shfl_xor(p0, o);
      float mn = fmaxf(m, p0);
      float sc  = __expf(m - mn);
      float pe0 = __expf(p0 - mn);
      denom = denom * sc + pe0;
#pragma unroll
      for (int i = 0; i < 4; ++i) acc[i] = acc[i] * sc + pe0 * bf2f(v0[i]);
      m = mn;
    }
  }
  float inv = 1.f / (denom + 1e-16f);
  float r[4];
#pragma unroll
  for (int i = 0; i < 4; ++i) {
    float mine = acc[i] * inv;
    r[i] = mine + __shfl_xor(mine, 32);   // add other head's same component
  }
  if (lane < 32) {
    const float* sp2 = s2 + (size_t)n * 128 + lane * 4;
    float* op = out + (size_t)n * 128 + lane * 4;
    float4 ov;
    ov.x = sp2[0] + 0.5f * r[0];
    ov.y = sp2[1] + 0.5f * r[1];
    ov.z = sp2[2] + 0.5f * r[2];
    ov.w = sp2[3] + 0.5f * r[3];
    *(float4*)op = ov;
  }
}

// ---------------------------------------------------------------- launch
extern "C" void kernel_launch(void* const* d_in, const int* in_sizes, int n_in,
                              void* d_out, int out_size, void* d_ws, size_t ws_size,
                              hipStream_t stream) {
  const float* x   = (const float*)d_in[0];
  const int*   ei  = (const int*)d_in[1];
  const float* Wq1 = (const float*)d_in[2];  const float* bq1 = (const float*)d_in[3];
  const float* Wk1 = (const float*)d_in[4];  const float* bk1 = (const float*)d_in[5];
  const float* Wv1 = (const float*)d_in[6];  const float* bv1 = (const float*)d_in[7];
  const float* Ws1 = (const float*)d_in[8];  const float* bs1 = (const float*)d_in[9];
  const float* Wq2 = (const float*)d_in[10]; const float* bq2 = (const float*)d_in[11];
  const float* Wk2 = (const float*)d_in[12]; const float* bk2 = (const float*)d_in[13];
  const float* Wv2 = (const float*)d_in[14]; const float* bv2 = (const float*)d_in[15];
  const float* Ws2 = (const float*)d_in[16]; const float* bs2 = (const float*)d_in[17];
  float* out = (float*)d_out;

  const int* src = ei;
  const int* dst = ei + N_EDGES;

  char* ws = (char*)d_ws;
  size_t off = 0;
  auto take = [&](size_t bytes) -> void* {
    void* p = ws + off;
    off = (off + bytes + 255) & ~(size_t)255;
    return p;
  };
  int* counts  = (int*)take(N_NODES * 4);
  int* offsets = (int*)take((N_NODES + 1) * 4);
  int* cursor  = (int*)take(N_NODES * 4);
  int* csr_src = (int*)take(N_EDGES * 4);
  __hip_bfloat16* xb   = (__hip_bfloat16*)take((size_t)N_NODES * 128 * 2);
  // NOTE: Wt1 (1536x128) and Wst1 (512x128) must be contiguous (merged Bt of
  // 2048 rows); sizes are multiples of 256 B so take() keeps them adjacent.
  __hip_bfloat16* Wt1  = (__hip_bfloat16*)take((size_t)1536 * 128 * 2);
  __hip_bfloat16* Wst1 = (__hip_bfloat16*)take((size_t)512 * 128 * 2);
  __hip_bfloat16* Wt2  = (__hip_bfloat16*)take((size_t)768 * 512 * 2);
  __hip_bfloat16* Wst2 = (__hip_bfloat16*)take((size_t)128 * 512 * 2);
  float* b1 = (float*)take(2048 * 4);
  float* b2 = (float*)take(896 * 4);
  __hip_bfloat16* qkv1 = (__hip_bfloat16*)take((size_t)N_NODES * 1536 * 2);
  float*          s1   = (float*)take((size_t)N_NODES * 512 * 4);
  __hip_bfloat16* hb   = (__hip_bfloat16*)take((size_t)N_NODES * 512 * 2);
  __hip_bfloat16* qkv2 = (__hip_bfloat16*)take((size_t)N_NODES * 768 * 2);
  float*          s2   = (float*)take((size_t)N_NODES * 128 * 4);
  (void)ws_size;  // ~87 MB

  // CSR by dst (all kernel dispatches; no memset nodes in the graph)
  zero_kernel<<<(N_NODES + 255) / 256, 256, 0, stream>>>(counts);
  count_kernel<<<(N_EDGES + 255) / 256, 256, 0, stream>>>(dst, counts);
  scan_kernel<<<1, 256, 0, stream>>>(counts, offsets, cursor);
  fill_kernel<<<(N_EDGES + 255) / 256, 256, 0, stream>>>(src, dst, cursor, csr_src);

  // bf16 conversion + weight transpose-pack (one kernel)
  prep_kernel<<<(PREP_TOTAL + 255) / 256, 256, 0, stream>>>(
      x, Wq1, Wk1, Wv1, Ws1, Wq2, Wk2, Wv2, Ws2,
      bq1, bk1, bv1, bs1, bq2, bk2, bv2, bs2,
      xb, Wt1, Wst1, Wt2, Wst2, b1, b2);

  const int MBLK = (N_NODES + GBM - 1) / GBM;  // 79

  // layer 1: ONE merged GEMM, N=2048 (cols 0..1535 -> qkv1 bf16, 1536.. -> s1 fp32)
  gemm_mfma_split<<<dim3(2048 / GBN, MBLK), 256, 0, stream>>>(
      xb, Wt1, b1, qkv1, s1, N_NODES, 2048, 128, 1536);

  // layer 1 fused attention -> hb (bf16), one wave per node
  attn_l1<<<(N_NODES + 3) / 4, 256, 0, stream>>>(qkv1, s1, offsets, csr_src, hb);

  // layer 2: ONE merged GEMM, N=896 (cols 0..767 -> qkv2 bf16, 768.. -> s2 fp32)
  gemm_mfma_split<<<dim3(896 / GBN, MBLK), 256, 0, stream>>>(
      hb, Wt2, b2, qkv2, s2, N_NODES, 896, 512, 768);

  // layer 2 fused attention (mean over 2 heads): out = s2 + 0.5*sum (pure write)
  attn_l2<<<(N_NODES + 3) / 4, 256, 0, stream>>>(qkv2, s2, offsets, csr_src, out);
}